// Round 1
// baseline (405.600 us; speedup 1.0000x reference)
//
#include <hip/hip_runtime.h>

#define NPIX   (1024*1024)
#define NBATCH 16
#define NBINS  256

__device__ __forceinline__ float clamp01(float x) {
    return fminf(fmaxf(x, 0.0f), 1.0f);
}

// ---------------------------------------------------------------------------
// Pass 1: per-batch 256-bin histogram of the Y channel.
// grid = (blocks_per_batch, NBATCH), block = 256
// ---------------------------------------------------------------------------
__global__ void __launch_bounds__(256)
hist_kernel(const float* __restrict__ img, unsigned int* __restrict__ hist) {
    const int b = blockIdx.y;
    __shared__ unsigned int lh[NBINS];
    if (threadIdx.x < NBINS) lh[threadIdx.x] = 0u;
    __syncthreads();

    const float* base = img + (size_t)b * 3 * NPIX;
    const float4* r4 = (const float4*)(base);
    const float4* g4 = (const float4*)(base + NPIX);
    const float4* b4 = (const float4*)(base + 2 * NPIX);

    const int n4 = NPIX / 4;
    const int stride = gridDim.x * blockDim.x;
    for (int i = blockIdx.x * blockDim.x + threadIdx.x; i < n4; i += stride) {
        float4 rv = r4[i], gv = g4[i], bv = b4[i];
        float rr[4] = {rv.x, rv.y, rv.z, rv.w};
        float gg[4] = {gv.x, gv.y, gv.z, gv.w};
        float bb[4] = {bv.x, bv.y, bv.z, bv.w};
#pragma unroll
        for (int k = 0; k < 4; ++k) {
            float r = clamp01(rr[k]);
            float g = clamp01(gg[k]);
            float bl = clamp01(bb[k]);
            float y = 0.299f * r + 0.587f * g + 0.114f * bl;
            float flat = y * 255.0f;                       // in [0, 255]
            int bin = (int)floorf(flat * (256.0f / 255.0f));
            bin = bin < 0 ? 0 : (bin > NBINS - 1 ? NBINS - 1 : bin);
            atomicAdd(&lh[bin], 1u);
        }
    }
    __syncthreads();
    if (threadIdx.x < NBINS)
        atomicAdd(&hist[b * NBINS + threadIdx.x], lh[threadIdx.x]);
}

// ---------------------------------------------------------------------------
// Pass 2: build LUT per batch. grid = NBATCH blocks, block = 256.
// Replicates:
//   last_idx = last nonzero bin (argmax over reversed nz)
//   step = floor((sum - histo[last_idx]) / 255)
//   lut  = floor((cumsum(histo) + floor(step/2)) / max(step,1))
//   lut  = [0, lut[:-1]], clipped to [0,255]
// ---------------------------------------------------------------------------
__global__ void __launch_bounds__(256)
lut_kernel(const unsigned int* __restrict__ hist,
           float* __restrict__ lut, float* __restrict__ stepflag) {
    const int b = blockIdx.x;
    const int i = threadIdx.x;
    __shared__ float h[NBINS];
    __shared__ float scan[NBINS];
    __shared__ float s_step, s_half;

    h[i] = (float)hist[b * NBINS + i];
    __syncthreads();

    if (i == 0) {
        float total = 0.0f;
        int last = 0;   // all-zero impossible (sum == NPIX), matches argmax semantics
        for (int k = 0; k < NBINS; ++k) {
            float hv = h[k];
            total += hv;
            if (hv > 0.0f) last = k;
        }
        float step = floorf((total - h[last]) / 255.0f);
        s_step = step;
        s_half = floorf(step / 2.0f);
        float cum = 0.0f;
        for (int k = 0; k < NBINS; ++k) { cum += h[k]; scan[k] = cum; }
        stepflag[b] = step;
    }
    __syncthreads();

    float step = s_step;
    float safe = fmaxf(step, 1.0f);
    float l = (i == 0) ? 0.0f : floorf((scan[i - 1] + s_half) / safe);
    l = fminf(fmaxf(l, 0.0f), 255.0f);
    lut[b * NBINS + i] = l;
}

// ---------------------------------------------------------------------------
// Pass 3: apply. Recompute YUV, map Y through LUT (index = trunc(y*255)!),
// convert back to RGB. grid = (blocks_per_batch, NBATCH), block = 256.
// ---------------------------------------------------------------------------
__global__ void __launch_bounds__(256)
apply_kernel(const float* __restrict__ img, float* __restrict__ out,
             const float* __restrict__ lut, const float* __restrict__ stepflag) {
    const int b = blockIdx.y;
    __shared__ float llut[NBINS];
    if (threadIdx.x < NBINS) llut[threadIdx.x] = lut[b * NBINS + threadIdx.x];
    __syncthreads();

    const float step = stepflag[b];
    const bool identity = (step == 0.0f);

    const float* base  = img + (size_t)b * 3 * NPIX;
    float*       obase = out + (size_t)b * 3 * NPIX;
    const float4* r4 = (const float4*)(base);
    const float4* g4 = (const float4*)(base + NPIX);
    const float4* b4 = (const float4*)(base + 2 * NPIX);
    float4* ro = (float4*)(obase);
    float4* go = (float4*)(obase + NPIX);
    float4* bo = (float4*)(obase + 2 * NPIX);

    const int n4 = NPIX / 4;
    const int stride = gridDim.x * blockDim.x;
    for (int i = blockIdx.x * blockDim.x + threadIdx.x; i < n4; i += stride) {
        float4 rv = r4[i], gv = g4[i], bv = b4[i];
        float rr[4] = {rv.x, rv.y, rv.z, rv.w};
        float gg[4] = {gv.x, gv.y, gv.z, gv.w};
        float bb[4] = {bv.x, bv.y, bv.z, bv.w};
        float orr[4], org[4], orb[4];
#pragma unroll
        for (int k = 0; k < 4; ++k) {
            float r = clamp01(rr[k]);
            float g = clamp01(gg[k]);
            float bl = clamp01(bb[k]);
            float y = 0.299f * r + 0.587f * g + 0.114f * bl;
            float u = -0.147f * r - 0.289f * g + 0.436f * bl;
            float v = 0.615f * r - 0.515f * g - 0.1f * bl;

            float flat = y * 255.0f;
            int gi = (int)flat;                 // trunc == floor (flat >= 0)
            gi = gi < 0 ? 0 : (gi > NBINS - 1 ? NBINS - 1 : gi);
            float ye = identity ? flat : llut[gi];
            ye = ye / 255.0f;

            orr[k] = ye + 1.14f * v;
            org[k] = ye - 0.396f * u - 0.581f * v;
            orb[k] = ye + 2.029f * u;
        }
        ro[i] = make_float4(orr[0], orr[1], orr[2], orr[3]);
        go[i] = make_float4(org[0], org[1], org[2], org[3]);
        bo[i] = make_float4(orb[0], orb[1], orb[2], orb[3]);
    }
}

extern "C" void kernel_launch(void* const* d_in, const int* in_sizes, int n_in,
                              void* d_out, int out_size, void* d_ws, size_t ws_size,
                              hipStream_t stream) {
    const float* img = (const float*)d_in[0];
    float* out = (float*)d_out;

    // workspace layout
    unsigned int* hist = (unsigned int*)d_ws;                       // 16*256 u32
    float* lut      = (float*)((char*)d_ws + NBATCH * NBINS * 4);   // 16*256 f32
    float* stepflag = (float*)((char*)d_ws + 2 * NBATCH * NBINS * 4); // 16 f32

    hipMemsetAsync(d_ws, 0, NBATCH * NBINS * sizeof(unsigned int), stream);

    const int BPB = 64;  // blocks per batch
    dim3 grid(BPB, NBATCH), block(256);
    hist_kernel<<<grid, block, 0, stream>>>(img, hist);
    lut_kernel<<<NBATCH, NBINS, 0, stream>>>(hist, lut, stepflag);
    apply_kernel<<<grid, block, 0, stream>>>(img, out, lut, stepflag);
}

// Round 5
// 377.095 us; speedup vs baseline: 1.0756x; 1.0756x over previous
//
#include <hip/hip_runtime.h>

#define NPIX   (1024*1024)
#define NBATCH 16
#define NBINS  256
#define NSUB   4
#define SUBST  257   // sub-histogram stride (pad to break bank aliasing)
#define BPB    128   // blocks per batch

typedef float v4f __attribute__((ext_vector_type(4)));

__device__ __forceinline__ float clamp01(float x) {
    return fminf(fmaxf(x, 0.0f), 1.0f);
}

// ---------------------------------------------------------------------------
// Pass 1: per-batch 256-bin histogram of the Y channel.
// grid = (BPB, NBATCH), block = 256
// 4 lane-interleaved sub-histograms (stride 257) cut same-address and bank
// collisions on the LDS atomics; reduced to global at the end.
// ---------------------------------------------------------------------------
__global__ void __launch_bounds__(256)
hist_kernel(const float* __restrict__ img, unsigned int* __restrict__ hist) {
    const int b = blockIdx.y;
    __shared__ unsigned int lh[NSUB * SUBST];
    for (int k = threadIdx.x; k < NSUB * SUBST; k += 256) lh[k] = 0u;
    __syncthreads();

    const int sub = (threadIdx.x & (NSUB - 1)) * SUBST;

    const float* base = img + (size_t)b * 3 * NPIX;
    const v4f* r4 = (const v4f*)(base);
    const v4f* g4 = (const v4f*)(base + NPIX);
    const v4f* b4 = (const v4f*)(base + 2 * NPIX);

    const int n4 = NPIX / 4;
    const int stride = gridDim.x * blockDim.x;
    for (int i = blockIdx.x * blockDim.x + threadIdx.x; i < n4; i += stride) {
        v4f rv = r4[i], gv = g4[i], bv = b4[i];
#pragma unroll
        for (int k = 0; k < 4; ++k) {
            float r = clamp01(rv[k]);
            float g = clamp01(gv[k]);
            float bl = clamp01(bv[k]);
            float y = 0.299f * r + 0.587f * g + 0.114f * bl;
            float flat = y * 255.0f;                       // in [0, 255]
            int bin = (int)floorf(flat * (256.0f / 255.0f));
            bin = bin < 0 ? 0 : (bin > NBINS - 1 ? NBINS - 1 : bin);
            atomicAdd(&lh[sub + bin], 1u);
        }
    }
    __syncthreads();
    // 256 threads: reduce 4 sub-histograms, one global atomic each
    {
        const int t = threadIdx.x;
        unsigned int s = lh[0 * SUBST + t] + lh[1 * SUBST + t] +
                         lh[2 * SUBST + t] + lh[3 * SUBST + t];
        atomicAdd(&hist[b * NBINS + t], s);
    }
}

// ---------------------------------------------------------------------------
// Pass 2: build LUT per batch — fully parallel (scan + tree reduce).
// grid = NBATCH, block = 256.
//   last_idx = last nonzero bin
//   step = floor((sum - histo[last_idx]) / 255)
//   lut  = floor((cumsum(histo) + floor(step/2)) / max(step,1))
//   lut  = [0, lut[:-1]], clipped to [0,255]
// ---------------------------------------------------------------------------
__global__ void __launch_bounds__(256)
lut_kernel(const unsigned int* __restrict__ hist,
           float* __restrict__ lut, float* __restrict__ stepflag) {
    const int b = blockIdx.x;
    const int i = threadIdx.x;
    __shared__ float sc[NBINS];   // becomes inclusive cumsum
    __shared__ int   li[NBINS];   // max-reduce of nonzero indices

    float hv = (float)hist[b * NBINS + i];
    sc[i] = hv;
    li[i] = (hv > 0.0f) ? i : -1;
    __syncthreads();

    // Hillis-Steele inclusive scan (8 steps)
#pragma unroll
    for (int off = 1; off < NBINS; off <<= 1) {
        float v = (i >= off) ? sc[i - off] : 0.0f;
        __syncthreads();
        sc[i] += v;
        __syncthreads();
    }
    // tree max-reduce for last nonzero index (8 steps)
#pragma unroll
    for (int off = NBINS / 2; off > 0; off >>= 1) {
        int v = (i < off) ? li[i + off] : -1;
        __syncthreads();
        if (i < off && v > li[i]) li[i] = v;
        __syncthreads();
    }

    const float total = sc[NBINS - 1];
    int last = li[0];
    if (last < 0) last = NBINS - 1;            // all-zero: argmax semantics
    const float hlast = sc[last] - (last > 0 ? sc[last - 1] : 0.0f);

    const float step = floorf((total - hlast) / 255.0f);
    const float half = floorf(step * 0.5f);
    const float safe = fmaxf(step, 1.0f);

    float l = (i == 0) ? 0.0f : floorf((sc[i - 1] + half) / safe);
    l = fminf(fmaxf(l, 0.0f), 255.0f);
    lut[b * NBINS + i] = l;
    if (i == 0) stepflag[b] = step;
}

// ---------------------------------------------------------------------------
// Pass 3: apply. Recompute YUV, map Y through LUT (index = trunc(y*255)!),
// convert back to RGB. Nontemporal stores keep img L3-resident.
// grid = (BPB, NBATCH), block = 256.
// ---------------------------------------------------------------------------
__global__ void __launch_bounds__(256)
apply_kernel(const float* __restrict__ img, float* __restrict__ out,
             const float* __restrict__ lut, const float* __restrict__ stepflag) {
    const int b = blockIdx.y;
    __shared__ float llut[NBINS];
    if (threadIdx.x < NBINS) llut[threadIdx.x] = lut[b * NBINS + threadIdx.x];
    __syncthreads();

    const float step = stepflag[b];
    const bool identity = (step == 0.0f);

    const float* base  = img + (size_t)b * 3 * NPIX;
    float*       obase = out + (size_t)b * 3 * NPIX;
    const v4f* r4 = (const v4f*)(base);
    const v4f* g4 = (const v4f*)(base + NPIX);
    const v4f* b4 = (const v4f*)(base + 2 * NPIX);
    v4f* ro = (v4f*)(obase);
    v4f* go = (v4f*)(obase + NPIX);
    v4f* bo = (v4f*)(obase + 2 * NPIX);

    const int n4 = NPIX / 4;
    const int stride = gridDim.x * blockDim.x;
    for (int i = blockIdx.x * blockDim.x + threadIdx.x; i < n4; i += stride) {
        v4f rv = r4[i], gv = g4[i], bv = b4[i];
        v4f orr, org, orb;
#pragma unroll
        for (int k = 0; k < 4; ++k) {
            float r = clamp01(rv[k]);
            float g = clamp01(gv[k]);
            float bl = clamp01(bv[k]);
            float y = 0.299f * r + 0.587f * g + 0.114f * bl;
            float u = -0.147f * r - 0.289f * g + 0.436f * bl;
            float v = 0.615f * r - 0.515f * g - 0.1f * bl;

            float flat = y * 255.0f;
            int gi = (int)flat;                 // trunc == floor (flat >= 0)
            gi = gi > NBINS - 1 ? NBINS - 1 : gi;
            float ye = identity ? flat : llut[gi];
            ye = ye * (1.0f / 255.0f);

            orr[k] = ye + 1.14f * v;
            org[k] = ye - 0.396f * u - 0.581f * v;
            orb[k] = ye + 2.029f * u;
        }
        __builtin_nontemporal_store(orr, &ro[i]);
        __builtin_nontemporal_store(org, &go[i]);
        __builtin_nontemporal_store(orb, &bo[i]);
    }
}

extern "C" void kernel_launch(void* const* d_in, const int* in_sizes, int n_in,
                              void* d_out, int out_size, void* d_ws, size_t ws_size,
                              hipStream_t stream) {
    const float* img = (const float*)d_in[0];
    float* out = (float*)d_out;

    // workspace layout
    unsigned int* hist = (unsigned int*)d_ws;                         // 16*256 u32
    float* lut      = (float*)((char*)d_ws + NBATCH * NBINS * 4);     // 16*256 f32
    float* stepflag = (float*)((char*)d_ws + 2 * NBATCH * NBINS * 4); // 16 f32

    (void)hipMemsetAsync(d_ws, 0, NBATCH * NBINS * sizeof(unsigned int), stream);

    dim3 grid(BPB, NBATCH), block(256);
    hist_kernel<<<grid, block, 0, stream>>>(img, hist);
    lut_kernel<<<NBATCH, NBINS, 0, stream>>>(hist, lut, stepflag);
    apply_kernel<<<grid, block, 0, stream>>>(img, out, lut, stepflag);
}